// Round 2
// baseline (327.485 us; speedup 1.0000x reference)
//
#include <hip/hip_runtime.h>
#include <hip/hip_bf16.h>

#define BB 64
#define CC 512
#define NPIX 784
#define KK 32
#define TOT (BB*NPIX)        // 50176
#define CHUNK 128            // c-chunk for k1a
#define NCH 4                // 512/128

// ---- ws layout (float offsets) ----
#define OFF_P   0                         // P:  [4][8][TOT][4]  = 6,422,528 floats
#define OFF_X2  (NCH*8*TOT*4)             // X2: [4][TOT]        =   200,704
#define OFF_A   (OFF_X2 + NCH*TOT)        // A:  [8][TOT][4]     = 1,605,632
#define OFF_WS  (OFF_A + 8*TOT*4)         // Wsum_p: [4][64][32] =     8,192
#define OFF_W   0                         // W: [4][64][32][512] = 4,194,304 (aliases P; P dead after k1b)
// total ws requirement: (OFF_WS + 4*64*32)*4 bytes ≈ 32.9 MB

// ---------------------------------------------------------------------------
// k1a: partial (csq - 2*x·c) over a 128-wide C chunk, + partial xsq.
// grid (196, 4), 256 thr. One thread per pixel per chunk.
// ---------------------------------------------------------------------------
__global__ __launch_bounds__(256) void k1a(const float* __restrict__ x,
                                           const float* __restrict__ cw,
                                           float* __restrict__ ws)
{
    __shared__ __align__(16) float cws[KK * CHUNK];   // 16 KB
    __shared__ float csqs[KK];

    const int t  = threadIdx.x;
    const int cc = blockIdx.y;
    const int c0 = cc * CHUNK;

    for (int i = t; i < KK * CHUNK; i += 256) {
        const int k = i >> 7, ci = i & 127;
        cws[i] = cw[k * CC + c0 + ci];
    }
    __syncthreads();
    if (t < KK) {
        float s = 0.f;
        for (int i = 0; i < CHUNK; ++i) {
            const int ci = (i + t) & 127;         // stagger: conflict-free
            const float v = cws[t * CHUNK + ci];
            s += v * v;
        }
        csqs[t] = s;
    }
    __syncthreads();

    const int flat = blockIdx.x * 256 + t;
    const int b = flat / NPIX;
    const int n = flat - b * NPIX;
    const float* xp = x + (size_t)b * CC * NPIX + (size_t)c0 * NPIX + n;

    float acc[KK];
#pragma unroll
    for (int k = 0; k < KK; ++k) acc[k] = 0.f;
    float xsq = 0.f;

    for (int ci = 0; ci < CHUNK; ci += 4) {
        const float xv0 = xp[(size_t)(ci + 0) * NPIX];
        const float xv1 = xp[(size_t)(ci + 1) * NPIX];
        const float xv2 = xp[(size_t)(ci + 2) * NPIX];
        const float xv3 = xp[(size_t)(ci + 3) * NPIX];
        xsq += xv0 * xv0 + xv1 * xv1 + xv2 * xv2 + xv3 * xv3;
        const float m0 = -2.f * xv0, m1 = -2.f * xv1, m2 = -2.f * xv2, m3 = -2.f * xv3;
#pragma unroll
        for (int k = 0; k < KK; ++k) {
            const float4 cv = *(const float4*)&cws[k * CHUNK + ci];
            acc[k] += m0 * cv.x + m1 * cv.y + m2 * cv.z + m3 * cv.w;
        }
    }

    float* P = ws + OFF_P;
#pragma unroll
    for (int kq = 0; kq < 8; ++kq) {
        float4 v;
        v.x = acc[kq * 4 + 0] + csqs[kq * 4 + 0];
        v.y = acc[kq * 4 + 1] + csqs[kq * 4 + 1];
        v.z = acc[kq * 4 + 2] + csqs[kq * 4 + 2];
        v.w = acc[kq * 4 + 3] + csqs[kq * 4 + 3];
        *(float4*)&P[((size_t)(cc * 8 + kq) * TOT + flat) * 4] = v;   // coalesced
    }
    ws[OFF_X2 + cc * TOT + flat] = xsq;
}

// ---------------------------------------------------------------------------
// k1b: reduce 4 chunk partials, softmax over k -> A[kq][flat][4]
// grid 392, 128 thr. One thread per pixel.
// ---------------------------------------------------------------------------
__global__ __launch_bounds__(128) void k1b(const float* __restrict__ scale,
                                           float* __restrict__ ws)
{
    const int flat = blockIdx.x * 128 + threadIdx.x;
    const float* P = ws + OFF_P;

    float s[KK];
#pragma unroll
    for (int k = 0; k < KK; ++k) s[k] = 0.f;
#pragma unroll
    for (int cc = 0; cc < NCH; ++cc) {
#pragma unroll
        for (int kq = 0; kq < 8; ++kq) {
            const float4 v = *(const float4*)&P[((size_t)(cc * 8 + kq) * TOT + flat) * 4];
            s[kq * 4 + 0] += v.x; s[kq * 4 + 1] += v.y;
            s[kq * 4 + 2] += v.z; s[kq * 4 + 3] += v.w;
        }
    }
    float xsq = 0.f;
#pragma unroll
    for (int cc = 0; cc < NCH; ++cc) xsq += ws[OFF_X2 + cc * TOT + flat];

    float m = -1e30f;
#pragma unroll
    for (int k = 0; k < KK; ++k) {
        s[k] = scale[k] * (xsq + s[k]);
        m = fmaxf(m, s[k]);
    }
    float ssum = 0.f;
#pragma unroll
    for (int k = 0; k < KK; ++k) {
        const float e = __expf(s[k] - m);
        s[k] = e;
        ssum += e;
    }
    const float inv = 1.f / ssum;

    float* A = ws + OFF_A;
#pragma unroll
    for (int kq = 0; kq < 8; ++kq) {
        const float4 v = make_float4(s[kq * 4 + 0] * inv, s[kq * 4 + 1] * inv,
                                     s[kq * 4 + 2] * inv, s[kq * 4 + 3] * inv);
        *(float4*)&A[((size_t)kq * TOT + flat) * 4] = v;   // coalesced
    }
}

// ---------------------------------------------------------------------------
// k2a: partial W[nz][b][k][c] = sum_{n in split} A[n][k] * x[c][n]
// grid (4 c-tiles, 64 b, 4 n-splits), 256 thr. Thread owns 2c x 8k.
// c-tile-0 blocks also emit partial wsum from the staged A tile.
// ---------------------------------------------------------------------------
#define CT2 128
#define NT2 49
#define NSPLIT 4
#define ASTRIDE 36   // padded row (floats), 16B-aligned

__global__ __launch_bounds__(256) void k2a(const float* __restrict__ x,
                                           float* __restrict__ ws)
{
    __shared__ __align__(16) float xs[CT2 * NT2];      // c-major, stride 49 (odd)
    __shared__ __align__(16) float As[NT2 * ASTRIDE];

    const int t  = threadIdx.x;
    const int b  = blockIdx.y;
    const int c0 = blockIdx.x * CT2;
    const int nz = blockIdx.z;
    const int ns = nz * (NPIX / NSPLIT);   // 196
    const int ci = t & 63;
    const int kg = t >> 6;                 // 0..3 -> k = kg*8 + kk

    const float* A = ws + OFF_A;
    const float* xb = x + (size_t)b * CC * NPIX;

    float acc0[8], acc1[8];
#pragma unroll
    for (int i = 0; i < 8; ++i) { acc0[i] = 0.f; acc1[i] = 0.f; }
    float wacc = 0.f;

    for (int n0 = ns; n0 < ns + (NPIX / NSPLIT); n0 += NT2) {
        __syncthreads();
        // stage x tile: 128 c-rows x 49 n (LDS addr == idx: conflict-free)
        for (int j = 0; j < 25; ++j) {
            const int idx = t + j * 256;
            if (idx < CT2 * NT2) {
                const int cr = idx / NT2;
                const int ni = idx - cr * NT2;
                xs[idx] = xb[(size_t)(c0 + cr) * NPIX + n0 + ni];
            }
        }
        // stage A tile: 49 n x 8 kq (float4), coalesced over flat
        for (int j = 0; j < 2; ++j) {
            const int idx = t + j * 256;
            if (idx < NT2 * 8) {
                const int kq = idx / NT2;
                const int ni = idx - kq * NT2;
                const float4 v = *(const float4*)&A[((size_t)kq * TOT + (size_t)b * NPIX + n0 + ni) * 4];
                *(float4*)&As[ni * ASTRIDE + kq * 4] = v;
            }
        }
        __syncthreads();

        for (int ni = 0; ni < NT2; ++ni) {
            const float xv0 = xs[ci * NT2 + ni];          // stride 49: 2-way only
            const float xv1 = xs[(ci + 64) * NT2 + ni];
            const float4 a0 = *(const float4*)&As[ni * ASTRIDE + kg * 8];      // wave-uniform
            const float4 a1 = *(const float4*)&As[ni * ASTRIDE + kg * 8 + 4];
            acc0[0] += xv0 * a0.x; acc0[1] += xv0 * a0.y;
            acc0[2] += xv0 * a0.z; acc0[3] += xv0 * a0.w;
            acc0[4] += xv0 * a1.x; acc0[5] += xv0 * a1.y;
            acc0[6] += xv0 * a1.z; acc0[7] += xv0 * a1.w;
            acc1[0] += xv1 * a0.x; acc1[1] += xv1 * a0.y;
            acc1[2] += xv1 * a0.z; acc1[3] += xv1 * a0.w;
            acc1[4] += xv1 * a1.x; acc1[5] += xv1 * a1.y;
            acc1[6] += xv1 * a1.z; acc1[7] += xv1 * a1.w;
        }
        // partial wsum from staged A (c-tile 0 only; banks distinct across t)
        if (blockIdx.x == 0 && t < KK) {
            float s = 0.f;
            for (int ni = 0; ni < NT2; ++ni) s += As[ni * ASTRIDE + t];
            wacc += s;
        }
    }

    float* W = ws + OFF_W;
#pragma unroll
    for (int kk = 0; kk < 8; ++kk) {
        const int k = kg * 8 + kk;
        W[((size_t)(nz * BB + b) * KK + k) * CC + c0 + ci]      = acc0[kk];
        W[((size_t)(nz * BB + b) * KK + k) * CC + c0 + ci + 64] = acc1[kk];
    }
    if (blockIdx.x == 0 && t < KK) ws[OFF_WS + (nz * BB + b) * KK + t] = wacc;
}

// ---------------------------------------------------------------------------
// k2b: out[b][k][c] = sum_nz W - (sum_nz wsum_p) * cw[k][c]
// grid 1024, 256 thr, one float4 of c per thread.
// ---------------------------------------------------------------------------
__global__ __launch_bounds__(256) void k2b(const float* __restrict__ cw,
                                           const float* __restrict__ ws,
                                           float* __restrict__ out)
{
    const int idx = blockIdx.x * 256 + threadIdx.x;   // float4 units, 262144 total
    const int cq = idx & 127;
    const int kb = idx >> 7;
    const int k  = kb & 31;
    const int b  = kb >> 5;

    const float* W = ws + OFF_W;
    float4 s = make_float4(0.f, 0.f, 0.f, 0.f);
#pragma unroll
    for (int nz = 0; nz < NSPLIT; ++nz) {
        const float4 v = *(const float4*)&W[((size_t)(nz * BB + b) * KK + k) * CC + cq * 4];
        s.x += v.x; s.y += v.y; s.z += v.z; s.w += v.w;
    }
    float wsum = 0.f;
#pragma unroll
    for (int nz = 0; nz < NSPLIT; ++nz) wsum += ws[OFF_WS + (nz * BB + b) * KK + k];

    const float4 c4 = *(const float4*)&cw[k * CC + cq * 4];
    float4 o;
    o.x = s.x - wsum * c4.x;
    o.y = s.y - wsum * c4.y;
    o.z = s.z - wsum * c4.z;
    o.w = s.w - wsum * c4.w;
    *(float4*)&out[(size_t)idx * 4] = o;
}

extern "C" void kernel_launch(void* const* d_in, const int* in_sizes, int n_in,
                              void* d_out, int out_size, void* d_ws, size_t ws_size,
                              hipStream_t stream) {
    const float* x     = (const float*)d_in[0];   // (64, 512, 28, 28)
    const float* cw    = (const float*)d_in[1];   // (32, 512)
    const float* scale = (const float*)d_in[2];   // (32,)
    float* out = (float*)d_out;                   // (64, 32, 512)
    float* ws  = (float*)d_ws;

    k1a<<<dim3(TOT / 256, NCH), dim3(256), 0, stream>>>(x, cw, ws);
    k1b<<<dim3(TOT / 128), dim3(128), 0, stream>>>(scale, ws);
    k2a<<<dim3(CC / CT2, BB, NSPLIT), dim3(256), 0, stream>>>(x, ws);
    k2b<<<dim3(BB * KK * CC / 4 / 256), dim3(256), 0, stream>>>(cw, ws, out);
}

// Round 3
// 247.378 us; speedup vs baseline: 1.3238x; 1.3238x over previous
//
#include <hip/hip_runtime.h>
#include <hip/hip_bf16.h>

#define BB 64
#define CC 512
#define NPIX 784
#define KK 32
#define TOT (BB*NPIX)        // 50176
#define CHUNK 128            // c-chunk for k1a
#define NCH 4                // 512/128

// ---- ws layout (float offsets) ----
#define OFF_P   0                         // P:  [4][8][TOT][4]  = 6,422,528 floats
#define OFF_X2  (NCH*8*TOT*4)             // X2: [4][TOT]        =   200,704
#define OFF_A   (OFF_X2 + NCH*TOT)        // A:  [8][TOT][4]     = 1,605,632
#define OFF_WS  (OFF_A + 8*TOT*4)         // Wsum_p: [2][64][32] =     4,096
#define OFF_W   0                         // W: [2][64][32][512] = 2,097,152 (aliases P; P dead after k1b)
// total ws ≈ 33 MB

// ---------------------------------------------------------------------------
// k1a: partial (csq - 2*x·c) over a 128-wide C chunk, + partial xsq.
// grid (196, 4), 256 thr. One thread per pixel per chunk.
// ---------------------------------------------------------------------------
__global__ __launch_bounds__(256) void k1a(const float* __restrict__ x,
                                           const float* __restrict__ cw,
                                           float* __restrict__ ws)
{
    __shared__ __align__(16) float cws[KK * CHUNK];   // 16 KB
    __shared__ float csqs[KK];

    const int t  = threadIdx.x;
    const int cc = blockIdx.y;
    const int c0 = cc * CHUNK;

    for (int i = t; i < KK * CHUNK; i += 256) {
        const int k = i >> 7, ci = i & 127;
        cws[i] = cw[k * CC + c0 + ci];
    }
    __syncthreads();
    if (t < KK) {
        float s = 0.f;
        for (int i = 0; i < CHUNK; ++i) {
            const int ci = (i + t) & 127;         // stagger: conflict-free
            const float v = cws[t * CHUNK + ci];
            s += v * v;
        }
        csqs[t] = s;
    }
    __syncthreads();

    const int flat = blockIdx.x * 256 + t;
    const int b = flat / NPIX;
    const int n = flat - b * NPIX;
    const float* xp = x + (size_t)b * CC * NPIX + (size_t)c0 * NPIX + n;

    float acc[KK];
#pragma unroll
    for (int k = 0; k < KK; ++k) acc[k] = 0.f;
    float xsq = 0.f;

    for (int ci = 0; ci < CHUNK; ci += 4) {
        const float xv0 = xp[(size_t)(ci + 0) * NPIX];
        const float xv1 = xp[(size_t)(ci + 1) * NPIX];
        const float xv2 = xp[(size_t)(ci + 2) * NPIX];
        const float xv3 = xp[(size_t)(ci + 3) * NPIX];
        xsq += xv0 * xv0 + xv1 * xv1 + xv2 * xv2 + xv3 * xv3;
        const float m0 = -2.f * xv0, m1 = -2.f * xv1, m2 = -2.f * xv2, m3 = -2.f * xv3;
#pragma unroll
        for (int k = 0; k < KK; ++k) {
            const float4 cv = *(const float4*)&cws[k * CHUNK + ci];
            acc[k] += m0 * cv.x + m1 * cv.y + m2 * cv.z + m3 * cv.w;
        }
    }

    float* P = ws + OFF_P;
#pragma unroll
    for (int kq = 0; kq < 8; ++kq) {
        float4 v;
        v.x = acc[kq * 4 + 0] + csqs[kq * 4 + 0];
        v.y = acc[kq * 4 + 1] + csqs[kq * 4 + 1];
        v.z = acc[kq * 4 + 2] + csqs[kq * 4 + 2];
        v.w = acc[kq * 4 + 3] + csqs[kq * 4 + 3];
        *(float4*)&P[((size_t)(cc * 8 + kq) * TOT + flat) * 4] = v;   // coalesced
    }
    ws[OFF_X2 + cc * TOT + flat] = xsq;
}

// ---------------------------------------------------------------------------
// k1b: reduce 4 chunk partials, softmax over k -> A[kq][flat][4]
// grid 392, 128 thr. One thread per pixel.
// ---------------------------------------------------------------------------
__global__ __launch_bounds__(128) void k1b(const float* __restrict__ scale,
                                           float* __restrict__ ws)
{
    const int flat = blockIdx.x * 128 + threadIdx.x;
    const float* P = ws + OFF_P;

    float s[KK];
#pragma unroll
    for (int k = 0; k < KK; ++k) s[k] = 0.f;
#pragma unroll
    for (int cc = 0; cc < NCH; ++cc) {
#pragma unroll
        for (int kq = 0; kq < 8; ++kq) {
            const float4 v = *(const float4*)&P[((size_t)(cc * 8 + kq) * TOT + flat) * 4];
            s[kq * 4 + 0] += v.x; s[kq * 4 + 1] += v.y;
            s[kq * 4 + 2] += v.z; s[kq * 4 + 3] += v.w;
        }
    }
    float xsq = 0.f;
#pragma unroll
    for (int cc = 0; cc < NCH; ++cc) xsq += ws[OFF_X2 + cc * TOT + flat];

    float m = -1e30f;
#pragma unroll
    for (int k = 0; k < KK; ++k) {
        s[k] = scale[k] * (xsq + s[k]);
        m = fmaxf(m, s[k]);
    }
    float ssum = 0.f;
#pragma unroll
    for (int k = 0; k < KK; ++k) {
        const float e = __expf(s[k] - m);
        s[k] = e;
        ssum += e;
    }
    const float inv = 1.f / ssum;

    float* A = ws + OFF_A;
#pragma unroll
    for (int kq = 0; kq < 8; ++kq) {
        const float4 v = make_float4(s[kq * 4 + 0] * inv, s[kq * 4 + 1] * inv,
                                     s[kq * 4 + 2] * inv, s[kq * 4 + 3] * inv);
        *(float4*)&A[((size_t)kq * TOT + flat) * 4] = v;   // coalesced
    }
}

// ---------------------------------------------------------------------------
// k2a: partial W[nz][b][k][c] = sum_{n in split} A[n][k] * x[c][n]
// grid (8 c-tiles, 64 b, 2 n-splits) = 1024 blocks, 256 thr.
// thread t: c = c0 + (t&63), k in [(t>>6)*8, +8). Only 8 accumulators.
// NT=56 (784 = 14*56): all staging counts are exact multiples -> no spill.
// ---------------------------------------------------------------------------
#define CT2 64
#define NT2 56
#define NSPLIT 2
#define NPB (NPIX / NSPLIT)   // 392 = 7*56
#define XSTR (NT2 + 1)        // 57: odd -> 2-way-only bank aliasing (free)
#define ASTR 36               // padded A row stride (floats), 16B aligned

__global__ __launch_bounds__(256) void k2a(const float* __restrict__ x,
                                           float* __restrict__ ws)
{
    __shared__ __align__(16) float xs[CT2 * XSTR];   // 14.6 KB
    __shared__ __align__(16) float As[NT2 * ASTR];   //  8.1 KB
    __shared__ float wred[4][KK];

    const int t  = threadIdx.x;
    const int b  = blockIdx.y;
    const int c0 = blockIdx.x * CT2;
    const int nz = blockIdx.z;
    const int ci = t & 63;
    const int kg = t >> 6;          // 0..3
    const int k0 = kg * 8;

    const float* Ag = ws + OFF_A;
    const float* xb = x + (size_t)b * CC * NPIX;
    const size_t bn = (size_t)b * NPIX;

    float acc[8];
#pragma unroll
    for (int i = 0; i < 8; ++i) acc[i] = 0.f;
    float wacc = 0.f;

    for (int n0 = nz * NPB; n0 < nz * NPB + NPB; n0 += NT2) {
        __syncthreads();
        // stage x tile: 64 c-rows x 56 n = 3584 elems = 14/thread exact
#pragma unroll 2
        for (int j = 0; j < (CT2 * NT2) / 256; ++j) {
            const int idx = t + j * 256;
            const int cr = idx / NT2;
            const int ni = idx - cr * NT2;
            xs[cr * XSTR + ni] = xb[(size_t)(c0 + cr) * NPIX + n0 + ni];
        }
        // stage A tile: 56 n x 8 kq float4 = 448 float4, coalesced in ni
        {
            const int idx = t;                       // 0..255
            const int kq = idx / NT2, ni = idx - kq * NT2;
            const float4 v = *(const float4*)&Ag[((size_t)kq * TOT + bn + n0 + ni) * 4];
            *(float4*)&As[ni * ASTR + kq * 4] = v;
            const int idx2 = t + 256;
            if (idx2 < NT2 * 8) {
                const int kq2 = idx2 / NT2, ni2 = idx2 - kq2 * NT2;
                const float4 v2 = *(const float4*)&Ag[((size_t)kq2 * TOT + bn + n0 + ni2) * 4];
                *(float4*)&As[ni2 * ASTR + kq2 * 4] = v2;
            }
        }
        __syncthreads();

        // wsum partial: distributed, 14 rows per wave, lanes 0..31 = k
        if (ci < KK) {
#pragma unroll 2
            for (int j = 0; j < NT2 / 4; ++j)
                wacc += As[(kg * (NT2 / 4) + j) * ASTR + ci];
        }

#pragma unroll 4
        for (int ni = 0; ni < NT2; ++ni) {
            const float xv = xs[ci * XSTR + ni];
            const float4 a0 = *(const float4*)&As[ni * ASTR + k0];       // wave-uniform: broadcast
            const float4 a1 = *(const float4*)&As[ni * ASTR + k0 + 4];
            acc[0] += xv * a0.x; acc[1] += xv * a0.y;
            acc[2] += xv * a0.z; acc[3] += xv * a0.w;
            acc[4] += xv * a1.x; acc[5] += xv * a1.y;
            acc[6] += xv * a1.z; acc[7] += xv * a1.w;
        }
    }

    // reduce wsum partials across the 4 waves
    if (ci < KK) wred[kg][ci] = wacc;
    __syncthreads();

    float* W = ws + OFF_W;
#pragma unroll
    for (int kk = 0; kk < 8; ++kk)
        W[((size_t)(nz * BB + b) * KK + k0 + kk) * CC + c0 + ci] = acc[kk];

    if (t < KK)
        ws[OFF_WS + (size_t)(nz * BB + b) * KK + t] =
            wred[0][t] + wred[1][t] + wred[2][t] + wred[3][t];
}

// ---------------------------------------------------------------------------
// k2b: out[b][k][c] = sum_nz W - (sum_nz wsum_p) * cw[k][c]
// grid 1024, 256 thr, one float4 of c per thread.
// ---------------------------------------------------------------------------
__global__ __launch_bounds__(256) void k2b(const float* __restrict__ cw,
                                           const float* __restrict__ ws,
                                           float* __restrict__ out)
{
    const int idx = blockIdx.x * 256 + threadIdx.x;   // float4 units, 262144 total
    const int cq = idx & 127;
    const int kb = idx >> 7;
    const int k  = kb & 31;
    const int b  = kb >> 5;

    const float* W = ws + OFF_W;
    float4 s = make_float4(0.f, 0.f, 0.f, 0.f);
#pragma unroll
    for (int nz = 0; nz < NSPLIT; ++nz) {
        const float4 v = *(const float4*)&W[((size_t)(nz * BB + b) * KK + k) * CC + cq * 4];
        s.x += v.x; s.y += v.y; s.z += v.z; s.w += v.w;
    }
    float wsum = 0.f;
#pragma unroll
    for (int nz = 0; nz < NSPLIT; ++nz) wsum += ws[OFF_WS + (size_t)(nz * BB + b) * KK + k];

    const float4 c4 = *(const float4*)&cw[k * CC + cq * 4];
    float4 o;
    o.x = s.x - wsum * c4.x;
    o.y = s.y - wsum * c4.y;
    o.z = s.z - wsum * c4.z;
    o.w = s.w - wsum * c4.w;
    *(float4*)&out[(size_t)idx * 4] = o;
}

extern "C" void kernel_launch(void* const* d_in, const int* in_sizes, int n_in,
                              void* d_out, int out_size, void* d_ws, size_t ws_size,
                              hipStream_t stream) {
    const float* x     = (const float*)d_in[0];   // (64, 512, 28, 28)
    const float* cw    = (const float*)d_in[1];   // (32, 512)
    const float* scale = (const float*)d_in[2];   // (32,)
    float* out = (float*)d_out;                   // (64, 32, 512)
    float* ws  = (float*)d_ws;

    k1a<<<dim3(TOT / 256, NCH), dim3(256), 0, stream>>>(x, cw, ws);
    k1b<<<dim3(TOT / 128), dim3(128), 0, stream>>>(scale, ws);
    k2a<<<dim3(CC / CT2, BB, NSPLIT), dim3(256), 0, stream>>>(x, ws);
    k2b<<<dim3(BB * KK * CC / 4 / 256), dim3(256), 0, stream>>>(cw, ws, out);
}

// Round 4
// 206.341 us; speedup vs baseline: 1.5871x; 1.1989x over previous
//
#include <hip/hip_runtime.h>
#include <hip/hip_bf16.h>

#define BB 64
#define CC 512
#define NPIX 784
#define KK 32
#define TOT (BB*NPIX)        // 50176

typedef __attribute__((ext_vector_type(8))) short short8;
typedef __attribute__((ext_vector_type(4))) float floatx4;

// ---- ws layout (float offsets) ----
#define OFF_A  0                          // A: [TOT][32]           = 1,605,632 floats
#define OFF_W  (TOT*KK)                   // W: [4][64][32][512]    = 4,194,304
#define OFF_WS (OFF_W + 4*BB*KK*CC)       // wsum_p: [4][64][32]    =     8,192
// total ~23.2 MB

__device__ __forceinline__ ushort f2bf(float f) {
    union { float f; unsigned u; } v; v.f = f;
    const unsigned u = v.u;
    return (ushort)((u + 0x7FFFu + ((u >> 16) & 1u)) >> 16);
}

// ---------------------------------------------------------------------------
// k1_mfma: A[flat][k] = softmax_k( scale_k * (xsq + csq_k - 2*x·c_k) )
// grid 784 blocks (64 px each; 784*64 = TOT exactly), 256 thr = 4 waves.
// Wave w computes px rows [w*16, w*16+16) x all 32 codewords via
// mfma_f32_16x16x32_bf16, C over 4 chunks of 128.
//   A-frag: A[m=lane&15][c=quad*8+j]   (x tile, LDS [px][c] bf16)
//   B-frag: B[c=quad*8+j][n=lane&15]   (cw tile, LDS [k][c] bf16)
//   D:      row(px)=quad*4+reg, col(k)=lane&15      [m89/m120 verified maps]
// xsq, csq accumulated in fp32 during staging; softmax fused in epilogue.
// ---------------------------------------------------------------------------
#define K1_PXT 64
#define K1_CCH 128
#define K1_STR (K1_CCH + 8)   // 136 shorts = 272 B rows (16B-aligned)

__global__ __launch_bounds__(256) void k1_mfma(const float* __restrict__ x,
                                               const float* __restrict__ cw,
                                               const float* __restrict__ scale,
                                               float* __restrict__ ws)
{
    __shared__ ushort xs[K1_PXT * K1_STR];   // 17408 B
    __shared__ ushort cs[KK * K1_STR];       //  8704 B
    __shared__ float xsq_p[4][K1_PXT];
    __shared__ float csq_p[KK][8];
    __shared__ float xsq_l[K1_PXT];
    __shared__ float csq_l[KK];

    const int t    = threadIdx.x;
    const int lane = t & 63;
    const int w    = t >> 6;
    const int col  = lane & 15;
    const int quad = lane >> 4;

    const int px0 = blockIdx.x * K1_PXT;

    // staging roles: x -> thread stages px=lane, c-subrange w*32..+32 per chunk
    const int flat = px0 + lane;
    const int sb = flat / NPIX;
    const int sn = flat - sb * NPIX;
    const float* xb = x + (size_t)sb * CC * NPIX + sn;
    //              cw -> thread stages row ck, 16 c per chunk
    const int ck  = t >> 3;   // 0..31
    const int ccp = t & 7;    // 0..7

    floatx4 acc0 = {0.f, 0.f, 0.f, 0.f};
    floatx4 acc1 = {0.f, 0.f, 0.f, 0.f};
    float xsqp = 0.f, csqp = 0.f;

    for (int cc4 = 0; cc4 < 4; ++cc4) {
        const int c0 = cc4 * K1_CCH;
        __syncthreads();                       // LDS reuse fence
        // ---- stage x tile (transpose to [px][c], bf16) ----
#pragma unroll
        for (int j8 = 0; j8 < 4; ++j8) {
            const int cl = w * 32 + j8 * 8;
            float v[8];
#pragma unroll
            for (int jj = 0; jj < 8; ++jj) v[jj] = xb[(size_t)(c0 + cl + jj) * NPIX];
#pragma unroll
            for (int jj = 0; jj < 8; ++jj) xsqp += v[jj] * v[jj];
            short8 pk;
#pragma unroll
            for (int jj = 0; jj < 8; ++jj) pk[jj] = (short)f2bf(v[jj]);
            *(short8*)&xs[lane * K1_STR + cl] = pk;
        }
        // ---- stage cw tile ([k][c], bf16) ----
#pragma unroll
        for (int h = 0; h < 2; ++h) {
            const int cl = ccp * 16 + h * 8;
            float v[8];
#pragma unroll
            for (int jj = 0; jj < 8; ++jj) v[jj] = cw[ck * CC + c0 + cl + jj];
#pragma unroll
            for (int jj = 0; jj < 8; ++jj) csqp += v[jj] * v[jj];
            short8 pk;
#pragma unroll
            for (int jj = 0; jj < 8; ++jj) pk[jj] = (short)f2bf(v[jj]);
            *(short8*)&cs[ck * K1_STR + cl] = pk;
        }
        __syncthreads();
        // ---- MFMA over this 128-c chunk ----
#pragma unroll
        for (int kc = 0; kc < 4; ++kc) {
            const short8 a  = *(const short8*)&xs[(w * 16 + col) * K1_STR + kc * 32 + quad * 8];
            const short8 b0 = *(const short8*)&cs[col * K1_STR        + kc * 32 + quad * 8];
            const short8 b1 = *(const short8*)&cs[(col + 16) * K1_STR + kc * 32 + quad * 8];
            acc0 = __builtin_amdgcn_mfma_f32_16x16x32_bf16(a, b0, acc0, 0, 0, 0);
            acc1 = __builtin_amdgcn_mfma_f32_16x16x32_bf16(a, b1, acc1, 0, 0, 0);
        }
    }

    // ---- reduce xsq / csq partials ----
    xsq_p[w][lane] = xsqp;
    csq_p[ck][ccp] = csqp;
    __syncthreads();
    if (t < K1_PXT)
        xsq_l[t] = xsq_p[0][t] + xsq_p[1][t] + xsq_p[2][t] + xsq_p[3][t];
    if (t >= 64 && t < 96) {
        const int k = t - 64;
        float s = 0.f;
#pragma unroll
        for (int p = 0; p < 8; ++p) s += csq_p[k][p];
        csq_l[k] = s;
    }
    __syncthreads();

    // ---- fused softmax epilogue ----
    const float s0 = scale[col], s1 = scale[col + 16];
    const float q0 = csq_l[col], q1 = csq_l[col + 16];
    float* Aout = ws + OFF_A;
#pragma unroll
    for (int r = 0; r < 4; ++r) {
        const int pl = w * 16 + quad * 4 + r;
        const float xq = xsq_l[pl];
        const float d0 = s0 * (xq + q0 - 2.f * acc0[r]);
        const float d1 = s1 * (xq + q1 - 2.f * acc1[r]);
        float mx = fmaxf(d0, d1);
        mx = fmaxf(mx, __shfl_xor(mx, 1));
        mx = fmaxf(mx, __shfl_xor(mx, 2));
        mx = fmaxf(mx, __shfl_xor(mx, 4));
        mx = fmaxf(mx, __shfl_xor(mx, 8));
        const float e0 = __expf(d0 - mx), e1 = __expf(d1 - mx);
        float sm = e0 + e1;
        sm += __shfl_xor(sm, 1);
        sm += __shfl_xor(sm, 2);
        sm += __shfl_xor(sm, 4);
        sm += __shfl_xor(sm, 8);
        const float inv = 1.f / sm;
        Aout[(size_t)(px0 + pl) * KK + col]      = e0 * inv;
        Aout[(size_t)(px0 + pl) * KK + col + 16] = e1 * inv;
    }
}

// ---------------------------------------------------------------------------
// k2a: partial W[nz][b][k][c] = sum_{n in split} A[n][k] * x[c][n]
// grid (4 c-tiles of 128, 64 b, 4 n-splits) = 1024 blocks, 256 thr.
// thread: 2 c (ci, ci+64) x 8 k -> 16 accumulators.
// ---------------------------------------------------------------------------
#define CT2 128
#define NT2 49
#define NSPLIT 4
#define NPB (NPIX / NSPLIT)   // 196 = 4*49
#define XSTR2 57              // odd stride: 2-way-only LDS aliasing (free)

__global__ __launch_bounds__(256) void k2a(const float* __restrict__ x,
                                           float* __restrict__ ws)
{
    __shared__ float xs[CT2 * XSTR2];   // 29184 B
    __shared__ float As[NT2 * KK];      //  6272 B
    __shared__ float wred[4][KK];

    const int t  = threadIdx.x;
    const int b  = blockIdx.y;
    const int c0 = blockIdx.x * CT2;
    const int nz = blockIdx.z;
    const int ci = t & 63;
    const int kg = t >> 6;
    const int k0 = kg * 8;

    const float* Ag = ws + OFF_A;
    const float* xb = x + (size_t)b * CC * NPIX;
    const size_t bn = (size_t)b * NPIX;

    float acc[16];
#pragma unroll
    for (int i = 0; i < 16; ++i) acc[i] = 0.f;
    float wacc = 0.f;

    for (int n0 = nz * NPB; n0 < nz * NPB + NPB; n0 += NT2) {
        __syncthreads();
        // stage x tile: 128 c x 49 n = 6272 = 24*256 + 128
#pragma unroll 4
        for (int j = 0; j < 24; ++j) {
            const int idx = t + j * 256;
            const int cr = idx / NT2;
            const int ni = idx - cr * NT2;
            xs[cr * XSTR2 + ni] = xb[(size_t)(c0 + cr) * NPIX + n0 + ni];
        }
        if (t < 128) {
            const int idx = t + 6144;
            const int cr = idx / NT2;
            const int ni = idx - cr * NT2;
            xs[cr * XSTR2 + ni] = xb[(size_t)(c0 + cr) * NPIX + n0 + ni];
        }
        // stage A tile: 49 n x 32 k = 1568 = 6*256 + 32 (coalesced rows)
#pragma unroll 3
        for (int j = 0; j < 6; ++j) {
            const int idx = t + j * 256;
            As[idx] = Ag[(bn + n0 + (idx >> 5)) * KK + (idx & 31)];
        }
        if (t < 32) {
            const int idx = t + 1536;
            As[idx] = Ag[(bn + n0 + (idx >> 5)) * KK + (idx & 31)];
        }
        __syncthreads();

        // distributed wsum partial (lanes 0..31 of each wave; rows strided)
        if (ci < KK) {
            for (int r = kg; r < NT2; r += 4) wacc += As[r * KK + ci];
        }

#pragma unroll 7
        for (int ni = 0; ni < NT2; ++ni) {
            const float xv0 = xs[ci * XSTR2 + ni];
            const float xv1 = xs[(ci + 64) * XSTR2 + ni];
            const float4 a0 = *(const float4*)&As[ni * KK + k0];       // wave-uniform broadcast
            const float4 a1 = *(const float4*)&As[ni * KK + k0 + 4];
            acc[0]  += xv0 * a0.x; acc[1]  += xv0 * a0.y;
            acc[2]  += xv0 * a0.z; acc[3]  += xv0 * a0.w;
            acc[4]  += xv0 * a1.x; acc[5]  += xv0 * a1.y;
            acc[6]  += xv0 * a1.z; acc[7]  += xv0 * a1.w;
            acc[8]  += xv1 * a0.x; acc[9]  += xv1 * a0.y;
            acc[10] += xv1 * a0.z; acc[11] += xv1 * a0.w;
            acc[12] += xv1 * a1.x; acc[13] += xv1 * a1.y;
            acc[14] += xv1 * a1.z; acc[15] += xv1 * a1.w;
        }
    }

    if (ci < KK) wred[kg][ci] = wacc;
    __syncthreads();

    float* W = ws + OFF_W;
#pragma unroll
    for (int kk = 0; kk < 8; ++kk) {
        W[((size_t)(nz * BB + b) * KK + k0 + kk) * CC + c0 + ci]      = acc[kk];
        W[((size_t)(nz * BB + b) * KK + k0 + kk) * CC + c0 + ci + 64] = acc[8 + kk];
    }
    if (t < KK)
        ws[OFF_WS + (size_t)(nz * BB + b) * KK + t] =
            wred[0][t] + wred[1][t] + wred[2][t] + wred[3][t];
}

// ---------------------------------------------------------------------------
// k2b: out[b][k][c] = sum_nz W - (sum_nz wsum_p) * cw[k][c]
// ---------------------------------------------------------------------------
__global__ __launch_bounds__(256) void k2b(const float* __restrict__ cw,
                                           const float* __restrict__ ws,
                                           float* __restrict__ out)
{
    const int idx = blockIdx.x * 256 + threadIdx.x;   // float4 units
    const int cq = idx & 127;
    const int kb = idx >> 7;
    const int k  = kb & 31;
    const int b  = kb >> 5;

    const float* W = ws + OFF_W;
    float4 s = make_float4(0.f, 0.f, 0.f, 0.f);
#pragma unroll
    for (int nz = 0; nz < NSPLIT; ++nz) {
        const float4 v = *(const float4*)&W[((size_t)(nz * BB + b) * KK + k) * CC + cq * 4];
        s.x += v.x; s.y += v.y; s.z += v.z; s.w += v.w;
    }
    float wsum = 0.f;
#pragma unroll
    for (int nz = 0; nz < NSPLIT; ++nz) wsum += ws[OFF_WS + (size_t)(nz * BB + b) * KK + k];

    const float4 c4 = *(const float4*)&cw[k * CC + cq * 4];
    float4 o;
    o.x = s.x - wsum * c4.x;
    o.y = s.y - wsum * c4.y;
    o.z = s.z - wsum * c4.z;
    o.w = s.w - wsum * c4.w;
    *(float4*)&out[(size_t)idx * 4] = o;
}

extern "C" void kernel_launch(void* const* d_in, const int* in_sizes, int n_in,
                              void* d_out, int out_size, void* d_ws, size_t ws_size,
                              hipStream_t stream) {
    const float* x     = (const float*)d_in[0];   // (64, 512, 28, 28)
    const float* cw    = (const float*)d_in[1];   // (32, 512)
    const float* scale = (const float*)d_in[2];   // (32,)
    float* out = (float*)d_out;                   // (64, 32, 512)
    float* ws  = (float*)d_ws;

    k1_mfma<<<dim3(TOT / K1_PXT), dim3(256), 0, stream>>>(x, cw, scale, ws);
    k2a<<<dim3(CC / CT2, BB, NSPLIT), dim3(256), 0, stream>>>(x, ws);
    k2b<<<dim3(BB * KK * CC / 4 / 256), dim3(256), 0, stream>>>(cw, ws, out);
}

// Round 5
// 194.982 us; speedup vs baseline: 1.6796x; 1.0583x over previous
//
#include <hip/hip_runtime.h>
#include <hip/hip_bf16.h>

#define BB 64
#define CC 512
#define NPIX 784
#define KK 32

typedef __attribute__((ext_vector_type(8))) short short8;
typedef __attribute__((ext_vector_type(4))) float floatx4;
typedef __attribute__((ext_vector_type(4))) unsigned short ushort4v;

// ws layout: A_T [64][32][784] bf16 = 3.2 MB  (only workspace user)

__device__ __forceinline__ unsigned short f2bf(float f) {
    union { float f; unsigned u; } v; v.f = f;
    return (unsigned short)((v.u + 0x7FFFu + ((v.u >> 16) & 1u)) >> 16);
}
__device__ __forceinline__ float bf2f(unsigned short h) {
    union { unsigned u; float f; } v; v.u = ((unsigned)h) << 16; return v.f;
}

// ---------------------------------------------------------------------------
// k1: A_T[b][k][px] = softmax_k( scale_k * (xsq + csq_k - 2*x·c_k) )  (bf16)
// grid (13, 64): batch-local px blocks of 64 (block 12 covers 16 px).
// 4 waves x (16 px x 32 k) via mfma_f32_16x16x32_bf16.
// A-fragments loaded DIRECT from global (no LDS staging, no chunk barriers):
//   lane: m=px=w*16+(l&15), kdim c = kc*32 + quad*8 + j  (stride-784 dwords,
//   64B segments, 4 waves together cover full 256B rows).
// cw staged once in LDS bf16; csq/xsq in fp32; softmax fused; epilogue
// transposes A through a 4.5KB LDS tile -> coalesced b128 global writes.
// ---------------------------------------------------------------------------
#define CW_S 520   // cs row stride (shorts); 1040B rows, 16B-aligned
#define AT_S 72    // At_l row stride; 144B rows, 16B-aligned

__global__ __launch_bounds__(256) void k1(const float* __restrict__ x,
                                          const float* __restrict__ cw,
                                          const float* __restrict__ scale,
                                          unsigned short* __restrict__ At)
{
    __shared__ unsigned short cs[KK * CW_S];    // 33280 B
    __shared__ unsigned short At_l[KK * AT_S];  //  4608 B
    __shared__ float xsq_l[4][16];
    __shared__ float csq_p[8][KK];
    __shared__ float csq_l[KK];

    const int t    = threadIdx.x;
    const int lane = t & 63;
    const int w    = t >> 6;
    const int col  = lane & 15;
    const int quad = lane >> 4;
    const int b    = blockIdx.y;
    const int px0  = blockIdx.x * 64;

    // ---- stage cw -> bf16 LDS (once) ----
#pragma unroll 4
    for (int j = 0; j < 16; ++j) {
        const int qidx = t + j * 256;
        const int row = qidx >> 7;          // /128 quads per row
        const int qc  = qidx & 127;
        const float4 v = *(const float4*)&cw[row * CC + qc * 4];
        ushort4v p; p.x = f2bf(v.x); p.y = f2bf(v.y); p.z = f2bf(v.z); p.w = f2bf(v.w);
        *(ushort4v*)&cs[row * CW_S + qc * 4] = p;
    }
    __syncthreads();
    // ---- csq partials (distributed over all 256 threads) ----
    {
        const int k = t & 31, part = t >> 5;
        float s = 0.f;
        for (int i = 0; i < 64; ++i) {
            const float v = bf2f(cs[k * CW_S + part * 64 + i]);
            s += v * v;
        }
        csq_p[part][k] = s;
    }
    __syncthreads();
    if (t < KK) {
        float s = 0.f;
#pragma unroll
        for (int p = 0; p < 8; ++p) s += csq_p[p][t];
        csq_l[t] = s;
    }

    // ---- MFMA main loop: fragments direct from global ----
    int px = px0 + w * 16 + col;
    if (px > NPIX - 1) px = NPIX - 1;       // clamp (block 12 pad rows)
    const float* xb = x + (size_t)b * CC * NPIX + px;

    floatx4 acc0 = {0.f, 0.f, 0.f, 0.f};
    floatx4 acc1 = {0.f, 0.f, 0.f, 0.f};
    float xsqp = 0.f;

#pragma unroll 4
    for (int kc = 0; kc < 16; ++kc) {
        const int cb = kc * 32 + quad * 8;
        float v[8];
#pragma unroll
        for (int j = 0; j < 8; ++j) v[j] = xb[(size_t)(cb + j) * NPIX];
#pragma unroll
        for (int j = 0; j < 8; ++j) xsqp += v[j] * v[j];
        short8 a;
#pragma unroll
        for (int j = 0; j < 8; ++j) a[j] = (short)f2bf(v[j]);
        const short8 b0 = *(const short8*)&cs[col * CW_S + cb];
        const short8 b1 = *(const short8*)&cs[(col + 16) * CW_S + cb];
        acc0 = __builtin_amdgcn_mfma_f32_16x16x32_bf16(a, b0, acc0, 0, 0, 0);
        acc1 = __builtin_amdgcn_mfma_f32_16x16x32_bf16(a, b1, acc1, 0, 0, 0);
    }

    // xsq: this lane covered only its quad's c-slice; sum across quads
    xsqp += __shfl_xor(xsqp, 16);
    xsqp += __shfl_xor(xsqp, 32);
    if (quad == 0) xsq_l[w][col] = xsqp;
    __syncthreads();    // xsq_l + csq_l ready

    // ---- fused softmax epilogue; write A bf16 into LDS transpose tile ----
    const float s0 = scale[col], s1 = scale[col + 16];
    const float q0 = csq_l[col], q1 = csq_l[col + 16];
#pragma unroll
    for (int r = 0; r < 4; ++r) {
        const float xq = xsq_l[w][quad * 4 + r];
        const float d0 = s0 * (xq + q0 - 2.f * acc0[r]);
        const float d1 = s1 * (xq + q1 - 2.f * acc1[r]);
        float mx = fmaxf(d0, d1);
        mx = fmaxf(mx, __shfl_xor(mx, 1));
        mx = fmaxf(mx, __shfl_xor(mx, 2));
        mx = fmaxf(mx, __shfl_xor(mx, 4));
        mx = fmaxf(mx, __shfl_xor(mx, 8));
        const float e0 = __expf(d0 - mx), e1 = __expf(d1 - mx);
        float sm = e0 + e1;
        sm += __shfl_xor(sm, 1);
        sm += __shfl_xor(sm, 2);
        sm += __shfl_xor(sm, 4);
        sm += __shfl_xor(sm, 8);
        const float inv = 1.f / sm;
        const int pxl = w * 16 + quad * 4 + r;
        At_l[col * AT_S + pxl]        = f2bf(e0 * inv);
        At_l[(col + 16) * AT_S + pxl] = f2bf(e1 * inv);
    }
    __syncthreads();

    // ---- coalesced transposed store: k-rows of 64 px (b128 per thread) ----
    {
        const int k = t >> 3, oct = t & 7;
        if (px0 + oct * 8 + 7 < NPIX) {
            const short8 v = *(const short8*)&At_l[k * AT_S + oct * 8];
            *(short8*)&At[((size_t)b * KK + k) * NPIX + px0 + oct * 8] = v;
        }
    }
}

// ---------------------------------------------------------------------------
// k2: out[b][k][c] = sum_n A_T[b][k][n]*x[b][c][n] - wsum[b][k]*cw[k][c]
// MFMA GEMM: m=k(32), n=c, kdim=px. grid (8 c-tiles of 64, 64 b) = 512 blocks.
// px chunks of 160 (zero-padded to 800). Wave w: c-sub w*16, both m-halves.
// wsum computed per-block from the staged A tiles (redundant, ~free);
// epilogue writes final out directly — no W round-trip, no third kernel.
// ---------------------------------------------------------------------------
#define K2_PT 160
#define K2_S  168   // LDS row stride (shorts); 336B rows, 16B-aligned

__global__ __launch_bounds__(256) void k2(const float* __restrict__ x,
                                          const float* __restrict__ cw,
                                          const unsigned short* __restrict__ At,
                                          float* __restrict__ out)
{
    __shared__ unsigned short xs[64 * K2_S];   // 21504 B
    __shared__ unsigned short as[KK * K2_S];   // 10752 B
    __shared__ float wsum_l[KK];

    const int t    = threadIdx.x;
    const int lane = t & 63;
    const int w    = t >> 6;
    const int col  = lane & 15;
    const int quad = lane >> 4;
    const int b    = blockIdx.y;
    const int c0   = blockIdx.x * 64;

    const float* xb = x + (size_t)b * CC * NPIX;
    const unsigned short* ab = At + (size_t)b * KK * NPIX;

    floatx4 acc0 = {0.f, 0.f, 0.f, 0.f};
    floatx4 acc1 = {0.f, 0.f, 0.f, 0.f};
    float wacc[8];
#pragma unroll
    for (int i = 0; i < 8; ++i) wacc[i] = 0.f;

    for (int ch = 0; ch < 5; ++ch) {
        const int pt0 = ch * K2_PT;
        __syncthreads();
        // stage x tile: 64 c x 160 px, fp32->bf16, b64 LDS writes
#pragma unroll 2
        for (int j = 0; j < 10; ++j) {
            const int qidx = t + j * 256;
            const int cr = qidx / 40, pq = qidx - cr * 40;
            const int gpx = pt0 + pq * 4;
            ushort4v p;
            if (gpx < NPIX) {
                const float4 v = *(const float4*)&xb[(size_t)(c0 + cr) * NPIX + gpx];
                p.x = f2bf(v.x); p.y = f2bf(v.y); p.z = f2bf(v.z); p.w = f2bf(v.w);
            } else { p.x = 0; p.y = 0; p.z = 0; p.w = 0; }
            *(ushort4v*)&xs[cr * K2_S + pq * 4] = p;
        }
        // stage A tile: 32 k x 160 px (bf16 straight copy)
#pragma unroll
        for (int j = 0; j < 5; ++j) {
            const int qidx = t + j * 256;
            const int k = qidx / 40, pq = qidx - k * 40;
            const int gpx = pt0 + pq * 4;
            ushort4v p;
            if (gpx < NPIX) p = *(const ushort4v*)&ab[(size_t)k * NPIX + gpx];
            else { p.x = 0; p.y = 0; p.z = 0; p.w = 0; }
            *(ushort4v*)&as[k * K2_S + pq * 4] = p;
        }
        __syncthreads();

        // wsum partials: wave w owns k = w*8..+8, lanes spread over px
#pragma unroll
        for (int kk = 0; kk < 8; ++kk) {
            const int k = w * 8 + kk;
            float v = bf2f(as[k * K2_S + lane]) + bf2f(as[k * K2_S + 64 + lane]);
            const float v3 = bf2f(as[k * K2_S + 128 + (lane & 31)]);
            wacc[kk] += v + ((lane < 32) ? v3 : 0.f);
        }

        // MFMA: 5 kdim steps x 2 m-halves
#pragma unroll
        for (int s = 0; s < 5; ++s) {
            const int off = s * 32 + quad * 8;
            const short8 av0 = *(const short8*)&as[col * K2_S + off];
            const short8 av1 = *(const short8*)&as[(col + 16) * K2_S + off];
            const short8 bv  = *(const short8*)&xs[(w * 16 + col) * K2_S + off];
            acc0 = __builtin_amdgcn_mfma_f32_16x16x32_bf16(av0, bv, acc0, 0, 0, 0);
            acc1 = __builtin_amdgcn_mfma_f32_16x16x32_bf16(av1, bv, acc1, 0, 0, 0);
        }
    }

    // reduce wsum partials across the full wave
#pragma unroll
    for (int kk = 0; kk < 8; ++kk) {
        float v = wacc[kk];
        v += __shfl_xor(v, 1);  v += __shfl_xor(v, 2);  v += __shfl_xor(v, 4);
        v += __shfl_xor(v, 8);  v += __shfl_xor(v, 16); v += __shfl_xor(v, 32);
        if (lane == 0) wsum_l[w * 8 + kk] = v;
    }
    __syncthreads();

    // epilogue: D row = k = quad*4+r (+16), col = c
    const int c = c0 + w * 16 + col;
#pragma unroll
    for (int r = 0; r < 4; ++r) {
        const int ka = quad * 4 + r, kb = ka + 16;
        out[((size_t)b * KK + ka) * CC + c] = acc0[r] - wsum_l[ka] * cw[ka * CC + c];
        out[((size_t)b * KK + kb) * CC + c] = acc1[r] - wsum_l[kb] * cw[kb * CC + c];
    }
}

extern "C" void kernel_launch(void* const* d_in, const int* in_sizes, int n_in,
                              void* d_out, int out_size, void* d_ws, size_t ws_size,
                              hipStream_t stream) {
    const float* x     = (const float*)d_in[0];   // (64, 512, 28, 28)
    const float* cw    = (const float*)d_in[1];   // (32, 512)
    const float* scale = (const float*)d_in[2];   // (32,)
    float* out = (float*)d_out;                   // (64, 32, 512)
    unsigned short* At = (unsigned short*)d_ws;   // A_T [64][32][784] bf16

    k1<<<dim3(13, BB), dim3(256), 0, stream>>>(x, cw, scale, At);
    k2<<<dim3(CC / 64, BB), dim3(256), 0, stream>>>(x, cw, At, out);
}

// Round 6
// 185.432 us; speedup vs baseline: 1.7661x; 1.0515x over previous
//
#include <hip/hip_runtime.h>
#include <hip/hip_bf16.h>

#define BB 64
#define CC 512
#define NPIX 784
#define KK 32
#define NSPL 7
#define PXB 112            // px per block = 7 MFMA tiles of 16
#define CW_S 520           // cw LDS row stride (shorts): 260 dw == 4 mod 32 -> conflict-free b128
#define XA_S 136           // xs/A_l row stride (shorts): 68 dw == 4 mod 32 -> conflict-free b128

typedef __attribute__((ext_vector_type(8))) short short8;
typedef __attribute__((ext_vector_type(4))) float floatx4;
typedef __attribute__((ext_vector_type(4))) unsigned short ushort4v;

// ws layout (float offsets): W_p [7][64][32][512] fp32, then wsum_p [7][64][32]
#define OFF_WP 0
#define OFF_WS (NSPL*BB*KK*CC)     // 7,340,032

__device__ __forceinline__ unsigned short f2bf(float f) {
    union { float f; unsigned u; } v; v.f = f;
    return (unsigned short)((v.u + 0x7FFFu + ((v.u >> 16) & 1u)) >> 16);
}
__device__ __forceinline__ float bf2f(unsigned short h) {
    union { unsigned u; float f; } v; v.u = ((unsigned)h) << 16; return v.f;
}

// ---------------------------------------------------------------------------
// Fused kernel: per (split, batch) block of 112 px.
//  Phase 1: A[k][px] = softmax_k(scale_k*(xsq+csq_k-2 x·c_k)) via MFMA,
//           x-frags direct from global (register double-buffered), A -> LDS bf16.
//  Phase 2: W_p[k][c] = sum_px A[k][px] x[c][px] via MFMA, x re-read (L2/L3-hot)
//           into LDS [c][px] bf16 in 4 c-chunks of 128. wsum from LDS A tile.
// ---------------------------------------------------------------------------
__global__ __launch_bounds__(256) void k_fused(const float* __restrict__ x,
                                               const float* __restrict__ cw,
                                               const float* __restrict__ scale,
                                               float* __restrict__ ws)
{
    __shared__ __align__(16) unsigned char u8[128 * XA_S * 2];   // 34816 B: cs (phase1) / xs (phase2)
    __shared__ __align__(16) unsigned short A_l[KK * XA_S];      //  8704 B
    __shared__ float csq_p[8][KK];
    __shared__ float csq_l[KK];
    __shared__ float wred[KK][8];

    unsigned short* cs = (unsigned short*)u8;   // [32][CW_S]  (phase 1 only)
    unsigned short* xs = (unsigned short*)u8;   // [128][XA_S] (phase 2 only)

    const int t     = threadIdx.x;
    const int lane  = t & 63;
    const int w     = t >> 6;
    const int col   = lane & 15;
    const int quad  = lane >> 4;
    const int split = blockIdx.x;
    const int b     = blockIdx.y;
    const int p0    = split * PXB;

    // ---- stage cw -> bf16 LDS ----
#pragma unroll 4
    for (int j = 0; j < 16; ++j) {
        const int qidx = t + j * 256;
        const int row = qidx >> 7, qc = qidx & 127;
        const float4 v = *(const float4*)&cw[row * CC + qc * 4];
        ushort4v p; p.x = f2bf(v.x); p.y = f2bf(v.y); p.z = f2bf(v.z); p.w = f2bf(v.w);
        *(ushort4v*)&cs[row * CW_S + qc * 4] = p;
    }
    __syncthreads();
    // ---- csq ----
    {
        const int k = t & 31, part = t >> 5;
        float s = 0.f;
        for (int i = 0; i < 64; ++i) {
            const float v = bf2f(cs[k * CW_S + part * 64 + i]);
            s += v * v;
        }
        csq_p[part][k] = s;
    }
    __syncthreads();
    if (t < KK) {
        float s = 0.f;
#pragma unroll
        for (int p = 0; p < 8; ++p) s += csq_p[p][t];
        csq_l[t] = s;
    }
    __syncthreads();

    const float s0 = scale[col], s1 = scale[col + 16];
    const float q0 = csq_l[col], q1 = csq_l[col + 16];

    // ================= Phase 1 =================
    for (int pt = w; pt < NSPL; pt += 4) {
        const int px = p0 + pt * 16 + col;
        const float* xb = x + (size_t)b * CC * NPIX + px;

        floatx4 acc0 = {0.f, 0.f, 0.f, 0.f};
        floatx4 acc1 = {0.f, 0.f, 0.f, 0.f};
        float xsqp = 0.f;
        float va[8], vb[8];

#pragma unroll
        for (int j = 0; j < 8; ++j) va[j] = xb[(size_t)(quad * 8 + j) * NPIX];

#pragma unroll
        for (int kc = 0; kc < 16; kc += 2) {
            // prefetch kc+1 into vb
            {
                const int cb = (kc + 1) * 32 + quad * 8;
#pragma unroll
                for (int j = 0; j < 8; ++j) vb[j] = xb[(size_t)(cb + j) * NPIX];
            }
            // process va (kc)
            {
#pragma unroll
                for (int j = 0; j < 8; ++j) xsqp += va[j] * va[j];
                short8 a;
#pragma unroll
                for (int j = 0; j < 8; ++j) a[j] = (short)f2bf(va[j]);
                const int cb0 = kc * 32 + quad * 8;
                const short8 b0 = *(const short8*)&cs[col * CW_S + cb0];
                const short8 b1 = *(const short8*)&cs[(col + 16) * CW_S + cb0];
                acc0 = __builtin_amdgcn_mfma_f32_16x16x32_bf16(a, b0, acc0, 0, 0, 0);
                acc1 = __builtin_amdgcn_mfma_f32_16x16x32_bf16(a, b1, acc1, 0, 0, 0);
            }
            // prefetch kc+2 into va
            if (kc + 2 < 16) {
                const int cb = (kc + 2) * 32 + quad * 8;
#pragma unroll
                for (int j = 0; j < 8; ++j) va[j] = xb[(size_t)(cb + j) * NPIX];
            }
            // process vb (kc+1)
            {
#pragma unroll
                for (int j = 0; j < 8; ++j) xsqp += vb[j] * vb[j];
                short8 a;
#pragma unroll
                for (int j = 0; j < 8; ++j) a[j] = (short)f2bf(vb[j]);
                const int cb1 = (kc + 1) * 32 + quad * 8;
                const short8 b0 = *(const short8*)&cs[col * CW_S + cb1];
                const short8 b1 = *(const short8*)&cs[(col + 16) * CW_S + cb1];
                acc0 = __builtin_amdgcn_mfma_f32_16x16x32_bf16(a, b0, acc0, 0, 0, 0);
                acc1 = __builtin_amdgcn_mfma_f32_16x16x32_bf16(a, b1, acc1, 0, 0, 0);
            }
        }

        // xsq: sum quad slices -> every lane has xsq for its col's px
        xsqp += __shfl_xor(xsqp, 16);
        xsqp += __shfl_xor(xsqp, 32);

        // fused softmax epilogue; D row = px = quad*4+r, col = k
#pragma unroll
        for (int r = 0; r < 4; ++r) {
            const float xq = __shfl(xsqp, quad * 4 + r);   // lane (quad*4+r) holds that px's xsq
            const float d0 = s0 * (xq + q0 - 2.f * acc0[r]);
            const float d1 = s1 * (xq + q1 - 2.f * acc1[r]);
            float mx = fmaxf(d0, d1);
            mx = fmaxf(mx, __shfl_xor(mx, 1));
            mx = fmaxf(mx, __shfl_xor(mx, 2));
            mx = fmaxf(mx, __shfl_xor(mx, 4));
            mx = fmaxf(mx, __shfl_xor(mx, 8));
            const float e0 = __expf(d0 - mx), e1 = __expf(d1 - mx);
            float sm = e0 + e1;
            sm += __shfl_xor(sm, 1);
            sm += __shfl_xor(sm, 2);
            sm += __shfl_xor(sm, 4);
            sm += __shfl_xor(sm, 8);
            const float inv = 1.f / sm;
            const int pxl = pt * 16 + quad * 4 + r;
            A_l[col * XA_S + pxl]        = f2bf(e0 * inv);
            A_l[(col + 16) * XA_S + pxl] = f2bf(e1 * inv);
        }
    }
    __syncthreads();   // A_l complete; cs dead from here

    // ---- wsum partials from A_l (valid px only) ----
    {
        const int k = t >> 3, part = t & 7;
        float s = 0.f;
#pragma unroll 7
        for (int i = 0; i < 14; ++i) s += bf2f(A_l[k * XA_S + part * 14 + i]);
        wred[k][part] = s;
    }
    // ---- zero px pads 112..127 (kdim padding for phase-2 MFMA) ----
    {
        const ushort4v z = {0, 0, 0, 0};
        if (t < 128) *(ushort4v*)&A_l[(t >> 2) * XA_S + PXB + (t & 3) * 4] = z;
#pragma unroll
        for (int jj = 0; jj < 2; ++jj) {
            const int q = t + jj * 256;   // 512 quads: 128 rows x 4
            *(ushort4v*)&xs[(q >> 2) * XA_S + PXB + (q & 3) * 4] = z;
        }
    }
    __syncthreads();

    if (t < KK) {
        float s = 0.f;
#pragma unroll
        for (int p = 0; p < 8; ++p) s += wred[t][p];
        ws[OFF_WS + (size_t)(split * BB + b) * KK + t] = s;
    }

    // ================= Phase 2 =================
    const float* xbase = x + (size_t)b * CC * NPIX + p0;
    float* Wp = ws + OFF_WP;

    for (int cch = 0; cch < 4; ++cch) {
        // stage x chunk [128 c][112 px] -> bf16 (re-read is L2/L3-hot)
#pragma unroll 2
        for (int j = 0; j < 14; ++j) {
            const int q = t + j * 256;           // 3584 float4 = 128 rows x 28
            const int row = q / 28, pq = q - row * 28;
            const float4 v = *(const float4*)&xbase[(size_t)(cch * 128 + row) * NPIX + pq * 4];
            ushort4v p; p.x = f2bf(v.x); p.y = f2bf(v.y); p.z = f2bf(v.z); p.w = f2bf(v.w);
            *(ushort4v*)&xs[row * XA_S + pq * 4] = p;
        }
        __syncthreads();

        floatx4 a00 = {0.f,0.f,0.f,0.f}, a01 = {0.f,0.f,0.f,0.f};
        floatx4 a10 = {0.f,0.f,0.f,0.f}, a11 = {0.f,0.f,0.f,0.f};
#pragma unroll
        for (int ks = 0; ks < 4; ++ks) {
            const int off = ks * 32 + quad * 8;
            const short8 av0 = *(const short8*)&A_l[col * XA_S + off];
            const short8 av1 = *(const short8*)&A_l[(col + 16) * XA_S + off];
            const short8 bv0 = *(const short8*)&xs[(w * 32 + col) * XA_S + off];
            const short8 bv1 = *(const short8*)&xs[(w * 32 + 16 + col) * XA_S + off];
            a00 = __builtin_amdgcn_mfma_f32_16x16x32_bf16(av0, bv0, a00, 0, 0, 0);
            a10 = __builtin_amdgcn_mfma_f32_16x16x32_bf16(av1, bv0, a10, 0, 0, 0);
            a01 = __builtin_amdgcn_mfma_f32_16x16x32_bf16(av0, bv1, a01, 0, 0, 0);
            a11 = __builtin_amdgcn_mfma_f32_16x16x32_bf16(av1, bv1, a11, 0, 0, 0);
        }

        // write W partials: D row = k (quad*4+r, +16), col = c
        const size_t sb = (size_t)(split * BB + b) * KK;
        const int cb = cch * 128 + w * 32;
#pragma unroll
        for (int r = 0; r < 4; ++r) {
            const int k0 = quad * 4 + r;
            Wp[(sb + k0) * CC + cb + col]           = a00[r];
            Wp[(sb + k0) * CC + cb + 16 + col]      = a01[r];
            Wp[(sb + k0 + 16) * CC + cb + col]      = a10[r];
            Wp[(sb + k0 + 16) * CC + cb + 16 + col] = a11[r];
        }
        __syncthreads();   // xs reads done before next chunk overwrites
    }
}

// ---------------------------------------------------------------------------
// k3: out[b][k][c] = sum_s W_p[s][b][k][c] - (sum_s wsum_p[s][b][k]) * cw[k][c]
// ---------------------------------------------------------------------------
__global__ __launch_bounds__(256) void k3(const float* __restrict__ cw,
                                          const float* __restrict__ ws,
                                          float* __restrict__ out)
{
    const int idx = blockIdx.x * 256 + threadIdx.x;   // 262144 float4s
    const int c4 = idx & 127;
    const int k  = (idx >> 7) & 31;
    const int b  = idx >> 12;

    const float* Wp = ws + OFF_WP;
    float4 s = make_float4(0.f, 0.f, 0.f, 0.f);
#pragma unroll
    for (int sp = 0; sp < NSPL; ++sp) {
        const float4 v = *(const float4*)&Wp[((size_t)(sp * BB + b) * KK + k) * CC + c4 * 4];
        s.x += v.x; s.y += v.y; s.z += v.z; s.w += v.w;
    }
    float wsum = 0.f;
#pragma unroll
    for (int sp = 0; sp < NSPL; ++sp) wsum += ws[OFF_WS + (size_t)(sp * BB + b) * KK + k];

    const float4 c4f = *(const float4*)&cw[k * CC + c4 * 4];
    float4 o;
    o.x = s.x - wsum * c4f.x;
    o.y = s.y - wsum * c4f.y;
    o.z = s.z - wsum * c4f.z;
    o.w = s.w - wsum * c4f.w;
    *(float4*)&out[(size_t)idx * 4] = o;
}

extern "C" void kernel_launch(void* const* d_in, const int* in_sizes, int n_in,
                              void* d_out, int out_size, void* d_ws, size_t ws_size,
                              hipStream_t stream) {
    const float* x     = (const float*)d_in[0];   // (64, 512, 28, 28)
    const float* cw    = (const float*)d_in[1];   // (32, 512)
    const float* scale = (const float*)d_in[2];   // (32,)
    float* out = (float*)d_out;                   // (64, 32, 512)
    float* ws  = (float*)d_ws;

    k_fused<<<dim3(NSPL, BB), dim3(256), 0, stream>>>(x, cw, scale, ws);
    k3<<<dim3(BB * KK * CC / 4 / 256), dim3(256), 0, stream>>>(cw, ws, out);
}